// Round 2
// baseline (1279.510 us; speedup 1.0000x reference)
//
#include <hip/hip_runtime.h>
#include <math.h>

#define NN 4096
#define QQ 1024
#define LDA 1032              // padded leading dim (16B-aligned rows)
#define AF (1025 * 1032)      // floats occupied by bordered matrix A (1025 rows)
#define NB 240                // grid size: exactly the p=0 syrk grid (15 x 16)

// ======== manual grid barrier (persistent blocks, device-scope) ========
// Monotone counter in global memory (reset by hipMemsetAsync each run).
// release-fence -> agent-scope arrival -> relaxed agent spin -> acquire-fence.
__device__ __forceinline__ void gsync(unsigned* bar, unsigned ep) {
    __syncthreads();
    if (threadIdx.x == 0) {
        __threadfence();   // release: make this block's writes device-visible
        __hip_atomic_fetch_add(bar, 1u, __ATOMIC_RELAXED, __HIP_MEMORY_SCOPE_AGENT);
        const unsigned target = ep * NB;
        while (__hip_atomic_load(bar, __ATOMIC_RELAXED, __HIP_MEMORY_SCOPE_AGENT) < target)
            __builtin_amdgcn_s_sleep(1);
        __threadfence();   // acquire: invalidate stale cached lines
    }
    __syncthreads();
}

// ======== rank-2 register potrf of a 64x64 tile (256 threads) ========
// Thread (i = tid&63, q = tid>>6) owns x[16] = row i, cols 16q..16q+15; all
// indices compile-time (spill-proof). Two columns factored per barrier.
__device__ __forceinline__ void potrf64_run(float (&x)[16], int i, int q,
                                            float2 (&col2)[2][64]) {
#pragma unroll
    for (int qk = 0; qk < 4; ++qk) {
#pragma unroll
        for (int c2 = 0; c2 < 8; ++c2) {
            const int k = qk * 16 + 2 * c2;
            const int ck = 2 * c2;
            const int b = c2 & 1;
            if (q == qk) {                        // wave-uniform
                float xk = x[ck];
                float d0 = __shfl(xk, k, 64);     // constexpr lane -> readlane
                float rs0 = rsqrtf(d0);
                float l0 = (i == k) ? d0 * rs0 : xk * rs0;
                if (i >= k) x[ck] = l0;
                float lk1 = __shfl(l0, k + 1, 64);        // L[k+1][k]
                float x1v = fmaf(-l0, lk1, x[ck + 1]);    // col k+1 after col-k update
                float d1 = __shfl(x1v, k + 1, 64);
                float rs1 = rsqrtf(d1);
                float l1 = (i == k + 1) ? d1 * rs1 : x1v * rs1;
                if (i >= k + 1) x[ck + 1] = l1;
                col2[b][i] = make_float2(l0, l1); // i<k lanes publish garbage, never read
            }
            __syncthreads();
            if (16 * q + 15 > k + 1 && i > k) {
                float2 lp = col2[b][i];
                const float4* cp = (const float4*)(&col2[b][16 * q]);
#pragma unroll
                for (int m2 = 0; m2 < 8; ++m2) {
                    float4 v = cp[m2];            // cols 16q+2m2 (x,y), 16q+2m2+1 (z,w)
                    if (16 * q + 2 * m2 > k + 1)
                        x[2 * m2] = fmaf(-lp.x, v.x, fmaf(-lp.y, v.y, x[2 * m2]));
                    if (16 * q + 2 * m2 + 1 > k + 1)
                        x[2 * m2 + 1] = fmaf(-lp.x, v.z, fmaf(-lp.y, v.w, x[2 * m2 + 1]));
                }
            }
        }
    }
}

// ======== template-unrolled trsm helpers ========
template<int K, int M>
struct TAcc {
    static __device__ __forceinline__ void run(const float (&Lb)[64][65], const float (&x)[64],
                                               float& a0, float& a1) {
        if constexpr (M < K)     a0 = fmaf(-Lb[K][M], x[M], a0);
        if constexpr (M + 1 < K) a1 = fmaf(-Lb[K][M + 1], x[M + 1], a1);
        if constexpr (M + 2 < K) TAcc<K, M + 2>::run(Lb, x, a0, a1);
    }
};
template<int K>
struct TStep {
    static __device__ __forceinline__ void run(const float (&Lb)[64][65], const float (&dinv)[64],
                                               float (&x)[64]) {
        if constexpr (K < 64) {
            float a0 = x[K], a1 = 0.f;
            TAcc<K, 0>::run(Lb, x, a0, a1);
            x[K] = (a0 + a1) * dinv[K];
            TStep<K + 1>::run(Lb, dinv, x);
        }
    }
};

// ======== single persistent kernel: all phases, gsync() between ========
__global__ __launch_bounds__(256, 1) void k_all(
    const float* __restrict__ yt, const float* __restrict__ yp,
    const int* __restrict__ idx, const float* __restrict__ dist,
    const float* __restrict__ se_p, const float* __restrict__ sbs,
    float* __restrict__ A, int* __restrict__ c, float* __restrict__ s,
    float* __restrict__ scal, float* __restrict__ t, float* __restrict__ w,
    float* __restrict__ sqc, unsigned* __restrict__ bar, float* __restrict__ out) {
    const int bid = blockIdx.x, tid = threadIdx.x;
    const int lane = tid & 63, wid = tid >> 6;
    unsigned ep = 0;

    __shared__ __align__(16) float PrRaw[64 * 68];
    __shared__ __align__(16) float PcRaw[64 * 68];
    __shared__ float2 col2[2][64];
    __shared__ float Lb[64][65];
    __shared__ float dinv[64];
    __shared__ float red[16];
    __shared__ float r1s[4], r2s[4];
    __shared__ float wl[64];

    // ---- phase 1: stats: r = yt-yp; s[q] += r; c[q] += 1; rr = sum r^2 ----
    if (bid < NN / 256) {
        int i = bid * 256 + tid;
        float r = yt[i] - yp[i];
        int q = idx[i];
        atomicAdd(&s[q], r);
        atomicAdd(&c[q], 1);
        float v = r * r;
        for (int o = 32; o > 0; o >>= 1) v += __shfl_down(v, o, 64);
        if (lane == 0) red[wid] = v;
        __syncthreads();
        if (tid == 0) atomicAdd(&scal[0], red[0] + red[1] + red[2] + red[3]);
    }
    gsync(bar, ++ep);

    // ---- phase 2: matvec: t = D s ; w = sqrt(c)*t ; sqc ; st = s.t ----
    {
        float sb0 = sbs[0];
        float inv2 = 1.0f / (2.0f * sbs[1]);
        for (int i = bid; i < QQ; i += NB) {
            const float* dr = dist + (size_t)i * QQ;
            float acc = 0.f;
            for (int j = tid; j < QQ; j += 256)
                acc += __expf(-dr[j] * inv2) * s[j];
            for (int o = 32; o > 0; o >>= 1) acc += __shfl_down(acc, o, 64);
            if (lane == 0) red[wid] = acc;
            __syncthreads();
            if (tid == 0) {
                float tot = (red[0] + red[1] + red[2] + red[3]) * sb0;
                t[i] = tot;
                float sq = sqrtf((float)c[i]);
                sqc[i] = sq;
                w[i] = sq * tot;
                atomicAdd(&scal[1], s[i] * tot);
            }
            __syncthreads();   // red reused next row-iteration
        }
    }
    gsync(bar, ++ep);

    // ---- phase 3: build bordered S: A[i][j] = I + inv_se*sqc_i*sqc_j*D_ij; row QQ = w ----
    {
        float sb0 = sbs[0];
        float inv2 = 1.0f / (2.0f * sbs[1]);
        float inv_se = 1.0f / se_p[0];
        for (int i = bid; i <= QQ; i += NB) {
            if (i == QQ) {
                for (int j = tid; j < QQ; j += 256) A[(size_t)QQ * LDA + j] = w[j];
            } else {
                float qi = sqc[i] * inv_se * sb0;
                const float* dr = dist + (size_t)i * QQ;
                float* ar_ = A + (size_t)i * LDA;
                for (int j = tid; j < QQ; j += 256)
                    ar_[j] = ((i == j) ? 1.0f : 0.0f) + qi * sqc[j] * __expf(-dr[j] * inv2);
            }
        }
    }
    gsync(bar, ++ep);

    // ---- phase 4: potrf of panel 0 (block 0 only) ----
    if (bid == 0) {
        int i = lane, q = wid;
        float* row = A + (size_t)i * LDA + 16 * q;
        float x[16];
#pragma unroll
        for (int m4 = 0; m4 < 4; ++m4) {
            float4 v = ((const float4*)row)[m4];
            x[4 * m4] = v.x; x[4 * m4 + 1] = v.y; x[4 * m4 + 2] = v.z; x[4 * m4 + 3] = v.w;
        }
        potrf64_run(x, i, q, col2);
#pragma unroll
        for (int m4 = 0; m4 < 4; ++m4)
            ((float4*)row)[m4] = make_float4(x[4 * m4], x[4 * m4 + 1], x[4 * m4 + 2], x[4 * m4 + 3]);
    }
    gsync(bar, ++ep);

    // ---- panel loop: trsm phase + (syrk + fused next-diag potrf) phase ----
#pragma unroll 1
    for (int p = 0; p < 15; ++p) {
        // ---- trsm: rows below panel (incl. bordered w-row): X * Lpp^T = A_panel ----
        {
            int t0v = (p + 1) * 64;
            int rows = (QQ + 1) - t0v;
            int nblk = (rows + 255) >> 8;
            if (bid < nblk) {
                const float* db = A + (size_t)(p * 64) * (LDA + 1);
                for (int kk = tid; kk < 4096; kk += 256) {
                    int ii = kk >> 6, jj = kk & 63;
                    Lb[ii][jj] = db[(size_t)ii * LDA + jj];
                }
                if (tid < 64) dinv[tid] = 1.0f / db[(size_t)tid * (LDA + 1)];
                __syncthreads();
                int r = t0v + bid * 256 + tid;
                if (r <= QQ) {
                    float* ar_ = A + (size_t)r * LDA + p * 64;
                    float x[64];
#pragma unroll
                    for (int jj = 0; jj < 16; ++jj) {
                        float4 v = ((const float4*)ar_)[jj];
                        x[4 * jj] = v.x; x[4 * jj + 1] = v.y;
                        x[4 * jj + 2] = v.z; x[4 * jj + 3] = v.w;
                    }
                    TStep<0>::run(Lb, dinv, x);
#pragma unroll
                    for (int jj = 0; jj < 16; ++jj)
                        ((float4*)ar_)[jj] = make_float4(x[4 * jj], x[4 * jj + 1],
                                                         x[4 * jj + 2], x[4 * jj + 3]);
                }
            }
        }
        gsync(bar, ++ep);
        // ---- syrk + fused next-panel potrf ----
        {
            int t0v = (p + 1) * 64;
            int rows = (QQ + 1) - t0v;
            int ncol = (QQ - t0v) / 64;
            int nr = (rows + 63) >> 6;
            if (bid < ncol * nr) {
                int bx = bid % ncol, by = bid / ncol;
                int r0 = t0v + by * 64;
                int c0 = t0v + bx * 64;
                if (c0 <= r0) {
                    bool dfuse = (bx == 0 && by == 0);
                    int tx = tid & 15, ty = tid >> 4;
                    int pc0 = p * 64;
                    for (int idx2 = tid; idx2 < 1024; idx2 += 256) {
                        int rr = idx2 >> 4, c4 = idx2 & 15;
                        int gr = r0 + rr;
                        float4 v = make_float4(0.f, 0.f, 0.f, 0.f);
                        if (gr <= QQ) v = *(const float4*)(A + (size_t)gr * LDA + pc0 + 4 * c4);
                        *(float4*)(PrRaw + rr * 68 + 4 * c4) = v;
                        if (!dfuse) {
                            float4 u = *(const float4*)(A + (size_t)(c0 + rr) * LDA + pc0 + 4 * c4);
                            *(float4*)(PcRaw + rr * 68 + 4 * c4) = u;
                        }
                    }
                    __syncthreads();
                    const float* PB = dfuse ? PrRaw : PcRaw;  // diag tile: same rows
                    float acc[4][4];
#pragma unroll
                    for (int ii = 0; ii < 4; ++ii)
#pragma unroll
                        for (int jj = 0; jj < 4; ++jj) acc[ii][jj] = 0.f;
                    float4 ar4[4], br4[4];
#pragma unroll 4
                    for (int k4 = 0; k4 < 16; ++k4) {
#pragma unroll
                        for (int ii = 0; ii < 4; ++ii)
                            ar4[ii] = *(const float4*)(PrRaw + (ty + 16 * ii) * 68 + 4 * k4);
#pragma unroll
                        for (int jj = 0; jj < 4; ++jj)
                            br4[jj] = *(const float4*)(PB + (tx + 16 * jj) * 68 + 4 * k4);
#pragma unroll
                        for (int ii = 0; ii < 4; ++ii)
#pragma unroll
                            for (int jj = 0; jj < 4; ++jj) {
                                acc[ii][jj] = fmaf(ar4[ii].x, br4[jj].x, acc[ii][jj]);
                                acc[ii][jj] = fmaf(ar4[ii].y, br4[jj].y, acc[ii][jj]);
                                acc[ii][jj] = fmaf(ar4[ii].z, br4[jj].z, acc[ii][jj]);
                                acc[ii][jj] = fmaf(ar4[ii].w, br4[jj].w, acc[ii][jj]);
                            }
                    }
                    if (!dfuse) {
#pragma unroll
                        for (int ii = 0; ii < 4; ++ii) {
                            int rr = r0 + ty + 16 * ii;
                            if (rr <= QQ) {
#pragma unroll
                                for (int jj = 0; jj < 4; ++jj) {
                                    float* pa = A + (size_t)rr * LDA + c0 + tx + 16 * jj;
                                    *pa -= acc[ii][jj];
                                }
                            }
                        }
                    } else {
                        // updated diag tile -> LDS (stride-65 view of PcRaw), then factor
#pragma unroll
                        for (int ii = 0; ii < 4; ++ii) {
                            int lr = ty + 16 * ii;
#pragma unroll
                            for (int jj = 0; jj < 4; ++jj) {
                                int lc = tx + 16 * jj;
                                float old = A[(size_t)(r0 + lr) * LDA + c0 + lc];
                                PcRaw[lr * 65 + lc] = old - acc[ii][jj];
                            }
                        }
                        __syncthreads();
                        int i = tid & 63, q = tid >> 6;
                        float x[16];
#pragma unroll
                        for (int m = 0; m < 16; ++m) x[m] = PcRaw[i * 65 + 16 * q + m];
                        potrf64_run(x, i, q, col2);
                        float* row = A + (size_t)(r0 + i) * LDA + c0 + 16 * q;
#pragma unroll
                        for (int m4 = 0; m4 < 4; ++m4)
                            ((float4*)row)[m4] = make_float4(x[4 * m4], x[4 * m4 + 1],
                                                             x[4 * m4 + 2], x[4 * m4 + 3]);
                    }
                }
            }
        }
        gsync(bar, ++ep);
    }

    // ---- final: block 0 solves bordered chunk 15 (into LDS) and reduces ----
    if (bid == 0) {
        const float* db = A + (size_t)960 * LDA + 960;  // last diag tile (factored)
        for (int kk = tid; kk < 4096; kk += 256) {
            int ii = kk >> 6, jj = kk & 63;
            Lb[ii][jj] = db[(size_t)ii * LDA + jj];
        }
        __syncthreads();
        if (tid < 64) {  // wave 0: parallel forward solve of the 64-elem chunk
            float xv = A[(size_t)QQ * LDA + 960 + tid];
            for (int k = 0; k < 64; ++k) {
                if (tid == k) xv /= Lb[k][k];
                float xk = __shfl(xv, k, 64);
                if (tid > k) xv = fmaf(-Lb[tid][k], xk, xv);
            }
            wl[tid] = xv;
        }
        __syncthreads();
        float v1 = 0.f, v2 = 0.f;
        for (int i = tid; i < QQ; i += 256) {
            v1 += __logf(A[(size_t)i * LDA + i]);
            float yv = (i >= 960) ? wl[i - 960] : A[(size_t)QQ * LDA + i];
            v2 += yv * yv;
        }
        v1 *= 2.0f;
        for (int o = 32; o > 0; o >>= 1) {
            v1 += __shfl_down(v1, o, 64);
            v2 += __shfl_down(v2, o, 64);
        }
        if (lane == 0) { r1s[wid] = v1; r2s[wid] = v2; }
        __syncthreads();
        if (tid == 0) {
            float ld = r1s[0] + r1s[1] + r1s[2] + r1s[3];
            float yy = r2s[0] + r2s[1] + r2s[2] + r2s[3];
            float se = se_p[0], inv = 1.0f / se;
            float rr = scal[0], st = scal[1];
            float quad = rr * inv - inv * inv * (st - inv * yy);
            float logdetV = (float)NN * __logf(se) + ld;
            out[0] = 0.5f * (float)NN * 1.8378770664093453f + 0.5f * logdetV + 0.5f * quad;
        }
    }
}

extern "C" void kernel_launch(void* const* d_in, const int* in_sizes, int n_in,
                              void* d_out, int out_size, void* d_ws, size_t ws_size,
                              hipStream_t stream) {
    const float* yt   = (const float*)d_in[0];
    const float* yp   = (const float*)d_in[1];
    const int*   idx  = (const int*)d_in[2];
    const float* dist = (const float*)d_in[3];
    const float* se   = (const float*)d_in[4];
    const float* sbs  = (const float*)d_in[5];
    float* out = (float*)d_out;

    float* W    = (float*)d_ws;
    float* A    = W;                      // 1025 x LDA
    int*   c    = (int*)(W + AF);         // 1024
    float* s    = W + AF + 1024;          // 1024
    float* scal = W + AF + 2048;          // rr, st
    float* t    = scal + 2;               // 1024
    float* w    = t + 1024;               // 1024
    float* sqc  = w + 1024;               // 1024
    // barrier counter lives in the never-touched pad of A row 0 (cols 1028-1029)
    unsigned* bar = (unsigned*)(W + 1028);

    // zero accumulators: c(1024 int) + s(1024 f) + scal(2 f), contiguous
    hipMemsetAsync(c, 0, (1024 + 1024 + 2) * sizeof(float), stream);
    // zero barrier counter (graph replay resets it every iteration)
    hipMemsetAsync(bar, 0, 2 * sizeof(unsigned), stream);

    k_all<<<dim3(NB), dim3(256), 0, stream>>>(yt, yp, idx, dist, se, sbs,
                                              A, c, s, scal, t, w, sqc, bar, out);
}

// Round 4
// 957.523 us; speedup vs baseline: 1.3363x; 1.3363x over previous
//
#include <hip/hip_runtime.h>
#include <math.h>

#define NN 4096
#define QQ 1024
#define LDA 1032              // padded leading dim (16B-aligned rows)
#define AF (1025 * 1032)      // floats occupied by bordered matrix A (1025 rows)
#define NB 136                // grid: max fused-syrk tiles at p=0 is 135; 136 = 8*17

// ======== tree grid barrier ========
// 8 line-separated arrival counters (17 blocks each), root counter, epoch flag.
// Arrival: release-fence -> add to line counter; line-last adds to root;
// overall-last stores epoch flag (release). Everyone polls flag (read-only),
// then acquire-fence. Counters monotone; reset by hipMemsetAsync per launch.
__device__ __forceinline__ void gsync(unsigned* cnt, unsigned* root,
                                      unsigned* flag, unsigned ep) {
    __syncthreads();   // drains all waves' stores
    if (threadIdx.x == 0) {
        __threadfence();   // release: make this block's writes device-visible
        unsigned old = __hip_atomic_fetch_add(&cnt[(blockIdx.x & 7) * 32], 1u,
                                              __ATOMIC_RELAXED, __HIP_MEMORY_SCOPE_AGENT);
        if (old + 1 == ep * (NB / 8)) {           // last on my line this epoch
            unsigned r = __hip_atomic_fetch_add(root, 1u,
                                                __ATOMIC_RELAXED, __HIP_MEMORY_SCOPE_AGENT);
            if (r + 1 == ep * 8)                  // last overall this epoch
                __hip_atomic_store(flag, ep, __ATOMIC_RELEASE, __HIP_MEMORY_SCOPE_AGENT);
        }
        while (__hip_atomic_load(flag, __ATOMIC_RELAXED, __HIP_MEMORY_SCOPE_AGENT) < ep)
            __builtin_amdgcn_s_sleep(2);
        __threadfence();   // acquire: invalidate stale cached lines
    }
    __syncthreads();
}

// ======== rank-2 register potrf of a 64x64 tile (256 threads) ========
__device__ __forceinline__ void potrf64_run(float (&x)[16], int i, int q,
                                            float2 (&col2)[2][64]) {
#pragma unroll
    for (int qk = 0; qk < 4; ++qk) {
#pragma unroll
        for (int c2 = 0; c2 < 8; ++c2) {
            const int k = qk * 16 + 2 * c2;
            const int ck = 2 * c2;
            const int b = c2 & 1;
            if (q == qk) {                        // wave-uniform
                float xk = x[ck];
                float d0 = __shfl(xk, k, 64);
                float rs0 = rsqrtf(d0);
                float l0 = (i == k) ? d0 * rs0 : xk * rs0;
                if (i >= k) x[ck] = l0;
                float lk1 = __shfl(l0, k + 1, 64);
                float x1v = fmaf(-l0, lk1, x[ck + 1]);
                float d1 = __shfl(x1v, k + 1, 64);
                float rs1 = rsqrtf(d1);
                float l1 = (i == k + 1) ? d1 * rs1 : x1v * rs1;
                if (i >= k + 1) x[ck + 1] = l1;
                col2[b][i] = make_float2(l0, l1);
            }
            __syncthreads();
            if (16 * q + 15 > k + 1 && i > k) {
                float2 lp = col2[b][i];
                const float4* cp = (const float4*)(&col2[b][16 * q]);
#pragma unroll
                for (int m2 = 0; m2 < 8; ++m2) {
                    float4 v = cp[m2];
                    if (16 * q + 2 * m2 > k + 1)
                        x[2 * m2] = fmaf(-lp.x, v.x, fmaf(-lp.y, v.y, x[2 * m2]));
                    if (16 * q + 2 * m2 + 1 > k + 1)
                        x[2 * m2 + 1] = fmaf(-lp.x, v.z, fmaf(-lp.y, v.w, x[2 * m2 + 1]));
                }
            }
        }
    }
}

// ======== template-unrolled trsm helpers ========
template<int K, int M>
struct TAcc {
    static __device__ __forceinline__ void run(const float (&Lb)[64][65], const float (&x)[64],
                                               float& a0, float& a1) {
        if constexpr (M < K)     a0 = fmaf(-Lb[K][M], x[M], a0);
        if constexpr (M + 1 < K) a1 = fmaf(-Lb[K][M + 1], x[M + 1], a1);
        if constexpr (M + 2 < K) TAcc<K, M + 2>::run(Lb, x, a0, a1);
    }
};
template<int K>
struct TStep {
    static __device__ __forceinline__ void run(const float (&Lb)[64][65], const float (&dinv)[64],
                                               float (&x)[64]) {
        if constexpr (K < 64) {
            float a0 = x[K], a1 = 0.f;
            TAcc<K, 0>::run(Lb, x, a0, a1);
            x[K] = (a0 + a1) * dinv[K];
            TStep<K + 1>::run(Lb, dinv, x);
        }
    }
};

// ======== single persistent kernel: 19 grid barriers total ========
__global__ __launch_bounds__(256, 1) void k_all(
    const float* __restrict__ yt, const float* __restrict__ yp,
    const int* __restrict__ idx, const float* __restrict__ dist,
    const float* __restrict__ se_p, const float* __restrict__ sbs,
    float* __restrict__ A, int* __restrict__ c, float* __restrict__ s,
    float* __restrict__ scal, float* __restrict__ t, float* __restrict__ w,
    float* __restrict__ sqc, unsigned* __restrict__ barc, unsigned* __restrict__ root,
    unsigned* __restrict__ flag, float* __restrict__ out) {
    const int bid = blockIdx.x, tid = threadIdx.x;
    const int lane = tid & 63, wid = tid >> 6;
    unsigned ep = 0;

    __shared__ __align__(16) float PrRaw[64 * 68];
    __shared__ __align__(16) float PcRaw[64 * 68];
    __shared__ float2 col2[2][64];
    __shared__ float Lb[64][65];
    __shared__ float dinv[64];
    __shared__ float red[4];
    __shared__ float r1s[4], r2s[4];
    __shared__ float wl[64];

    // ---- phase 1: stats ----
    if (bid < NN / 256) {
        int i = bid * 256 + tid;
        float r = yt[i] - yp[i];
        int q = idx[i];
        atomicAdd(&s[q], r);
        atomicAdd(&c[q], 1);
        float v = r * r;
        for (int o = 32; o > 0; o >>= 1) v += __shfl_down(v, o, 64);
        if (lane == 0) red[wid] = v;
        __syncthreads();
        if (tid == 0) atomicAdd(&scal[0], red[0] + red[1] + red[2] + red[3]);
    }
    gsync(barc, root, flag, ++ep);

    // ---- phase 2: matvec: t = D s ; w = sqrt(c)*t ; sqc ; st = s.t ----
    {
        float sb0 = sbs[0];
        float inv2 = 1.0f / (2.0f * sbs[1]);
        for (int i = bid; i < QQ; i += NB) {
            const float* dr = dist + (size_t)i * QQ;
            float acc = 0.f;
            for (int j = tid; j < QQ; j += 256)
                acc += __expf(-dr[j] * inv2) * s[j];
            for (int o = 32; o > 0; o >>= 1) acc += __shfl_down(acc, o, 64);
            if (lane == 0) red[wid] = acc;
            __syncthreads();
            if (tid == 0) {
                float tot = (red[0] + red[1] + red[2] + red[3]) * sb0;
                t[i] = tot;
                float sq = sqrtf((float)c[i]);
                sqc[i] = sq;
                w[i] = sq * tot;
                atomicAdd(&scal[1], s[i] * tot);
            }
            __syncthreads();
        }
    }
    gsync(barc, root, flag, ++ep);

    // ---- phase 3: build bordered S ----
    {
        float sb0 = sbs[0];
        float inv2 = 1.0f / (2.0f * sbs[1]);
        float inv_se = 1.0f / se_p[0];
        for (int i = bid; i <= QQ; i += NB) {
            if (i == QQ) {
                for (int j = tid; j < QQ; j += 256) A[(size_t)QQ * LDA + j] = w[j];
            } else {
                float qi = sqc[i] * inv_se * sb0;
                const float* dr = dist + (size_t)i * QQ;
                float* ar_ = A + (size_t)i * LDA;
                for (int j = tid; j < QQ; j += 256)
                    ar_[j] = ((i == j) ? 1.0f : 0.0f) + qi * sqc[j] * __expf(-dr[j] * inv2);
            }
        }
    }
    gsync(barc, root, flag, ++ep);

    // ---- phase 4: potrf of panel 0 (block 0) ----
    if (bid == 0) {
        int i = lane, q = wid;
        float* row = A + (size_t)i * LDA + 16 * q;
        float x[16];
#pragma unroll
        for (int m4 = 0; m4 < 4; ++m4) {
            float4 v = ((const float4*)row)[m4];
            x[4 * m4] = v.x; x[4 * m4 + 1] = v.y; x[4 * m4 + 2] = v.z; x[4 * m4 + 3] = v.w;
        }
        potrf64_run(x, i, q, col2);
#pragma unroll
        for (int m4 = 0; m4 < 4; ++m4)
            ((float4*)row)[m4] = make_float4(x[4 * m4], x[4 * m4 + 1], x[4 * m4 + 2], x[4 * m4 + 3]);
    }
    gsync(barc, root, flag, ++ep);

    // ---- panel loop: ONE phase per panel (fused trsm-in-LDS + syrk + diag potrf) ----
    // Off-diag L is never written back: it's consumed only by this panel's syrk.
    // w-row solved chunks: sum-of-squares accumulated into scal[2].
#pragma unroll 1
    for (int p = 0; p < 15; ++p) {
        int t0v = (p + 1) * 64;
        int rows = (QQ + 1) - t0v;
        int nr = (rows + 63) >> 6;          // last row-tile is exactly row QQ
        int ncol = (QQ - t0v) / 64;
        // triangular tile enumeration: cnt(by) = min(by+1, ncol)
        int by = -1, bx = 0, rem = bid;
        for (int b = 0; b < nr; ++b) {
            int cn = (b + 1 < ncol) ? (b + 1) : ncol;
            if (rem < cn) { by = b; bx = rem; break; }
            rem -= cn;
        }
        if (by >= 0) {
            int r0 = t0v + by * 64;
            int c0 = t0v + bx * 64;
            bool wrow = (by == nr - 1);           // tile row = row QQ only
            bool same_rc = (bx == by) && !wrow;   // diag tile (incl. dfuse)
            bool dfuse = (bx == 0 && by == 0);
            int pc0 = p * 64;
            const float* db = A + (size_t)pc0 * (LDA + 1);
            // stage raw panel tiles + Lb + dinv
            for (int idx2 = tid; idx2 < 1024; idx2 += 256) {
                int rr = idx2 >> 4, c4 = idx2 & 15;
                int gr = r0 + rr;
                float4 v = make_float4(0.f, 0.f, 0.f, 0.f);
                if (gr <= QQ) v = *(const float4*)(A + (size_t)gr * LDA + pc0 + 4 * c4);
                *(float4*)(PrRaw + rr * 68 + 4 * c4) = v;
                if (!same_rc) {
                    float4 u = *(const float4*)(A + (size_t)(c0 + rr) * LDA + pc0 + 4 * c4);
                    *(float4*)(PcRaw + rr * 68 + 4 * c4) = u;
                }
            }
            for (int kk = tid; kk < 4096; kk += 256) {
                int ii = kk >> 6, jj = kk & 63;
                Lb[ii][jj] = db[(size_t)ii * LDA + jj];
            }
            if (tid < 64) dinv[tid] = 1.0f / db[(size_t)tid * (LDA + 1)];
            __syncthreads();
            // trsm in LDS: wave 0 -> PrRaw rows, wave 1 -> PcRaw rows
            if (wid == 0 && wrow) {
                // wave-parallel single-row solve of the w-chunk (row 0 of tile)
                float xv = PrRaw[lane];
                for (int k = 0; k < 64; ++k) {
                    if (lane == k) xv *= dinv[k];
                    float xk = __shfl(xv, k, 64);
                    if (lane > k) xv = fmaf(-Lb[lane][k], xk, xv);
                }
                PrRaw[lane] = xv;
                if (bx == 0) {                    // one accumulator of sum(wchunk^2)
                    float v = xv * xv;
                    for (int o = 32; o > 0; o >>= 1) v += __shfl_down(v, o, 64);
                    if (lane == 0) atomicAdd(&scal[2], v);
                }
            } else {
                float* tp = nullptr;
                if (wid == 0) tp = PrRaw + lane * 68;               // !wrow here
                else if (wid == 1 && !same_rc) tp = PcRaw + lane * 68;
                if (tp) {
                    float x[64];
#pragma unroll
                    for (int m = 0; m < 64; ++m) x[m] = tp[m];
                    TStep<0>::run(Lb, dinv, x);
#pragma unroll
                    for (int m = 0; m < 64; ++m) tp[m] = x[m];
                }
            }
            __syncthreads();
            // syrk from trsm'd LDS tiles
            const float* PB = same_rc ? PrRaw : PcRaw;
            int tx = tid & 15, ty = tid >> 4;
            float acc[4][4];
#pragma unroll
            for (int ii = 0; ii < 4; ++ii)
#pragma unroll
                for (int jj = 0; jj < 4; ++jj) acc[ii][jj] = 0.f;
            float4 ar4[4], br4[4];
#pragma unroll 4
            for (int k4 = 0; k4 < 16; ++k4) {
#pragma unroll
                for (int ii = 0; ii < 4; ++ii)
                    ar4[ii] = *(const float4*)(PrRaw + (ty + 16 * ii) * 68 + 4 * k4);
#pragma unroll
                for (int jj = 0; jj < 4; ++jj)
                    br4[jj] = *(const float4*)(PB + (tx + 16 * jj) * 68 + 4 * k4);
#pragma unroll
                for (int ii = 0; ii < 4; ++ii)
#pragma unroll
                    for (int jj = 0; jj < 4; ++jj) {
                        acc[ii][jj] = fmaf(ar4[ii].x, br4[jj].x, acc[ii][jj]);
                        acc[ii][jj] = fmaf(ar4[ii].y, br4[jj].y, acc[ii][jj]);
                        acc[ii][jj] = fmaf(ar4[ii].z, br4[jj].z, acc[ii][jj]);
                        acc[ii][jj] = fmaf(ar4[ii].w, br4[jj].w, acc[ii][jj]);
                    }
            }
            if (!dfuse) {
#pragma unroll
                for (int ii = 0; ii < 4; ++ii) {
                    int rr = r0 + ty + 16 * ii;
                    if (rr <= QQ) {
#pragma unroll
                        for (int jj = 0; jj < 4; ++jj) {
                            float* pa = A + (size_t)rr * LDA + c0 + tx + 16 * jj;
                            *pa -= acc[ii][jj];
                        }
                    }
                }
            } else {
                // updated next diag tile -> LDS (stride-65 view of PcRaw), then factor
#pragma unroll
                for (int ii = 0; ii < 4; ++ii) {
                    int lr = ty + 16 * ii;
#pragma unroll
                    for (int jj = 0; jj < 4; ++jj) {
                        int lc = tx + 16 * jj;
                        float old = A[(size_t)(r0 + lr) * LDA + c0 + lc];
                        PcRaw[lr * 65 + lc] = old - acc[ii][jj];
                    }
                }
                __syncthreads();
                int i = tid & 63, q = tid >> 6;
                float x[16];
#pragma unroll
                for (int m = 0; m < 16; ++m) x[m] = PcRaw[i * 65 + 16 * q + m];
                potrf64_run(x, i, q, col2);
                float* row = A + (size_t)(r0 + i) * LDA + c0 + 16 * q;
#pragma unroll
                for (int m4 = 0; m4 < 4; ++m4)
                    ((float4*)row)[m4] = make_float4(x[4 * m4], x[4 * m4 + 1],
                                                     x[4 * m4 + 2], x[4 * m4 + 3]);
            }
        }
        gsync(barc, root, flag, ++ep);
    }

    // ---- final: block 0 solves bordered chunk 15 in LDS and reduces ----
    if (bid == 0) {
        const float* db = A + (size_t)960 * LDA + 960;  // last diag tile (factored)
        for (int kk = tid; kk < 4096; kk += 256) {
            int ii = kk >> 6, jj = kk & 63;
            Lb[ii][jj] = db[(size_t)ii * LDA + jj];
        }
        __syncthreads();
        if (tid < 64) {
            float xv = A[(size_t)QQ * LDA + 960 + tid];
            for (int k = 0; k < 64; ++k) {
                if (tid == k) xv /= Lb[k][k];
                float xk = __shfl(xv, k, 64);
                if (tid > k) xv = fmaf(-Lb[tid][k], xk, xv);
            }
            wl[tid] = xv;
        }
        __syncthreads();
        float v1 = 0.f, v2 = 0.f;
        for (int i = tid; i < QQ; i += 256) {
            v1 += __logf(A[(size_t)i * LDA + i]);
            if (i >= 960) { float yv = wl[i - 960]; v2 += yv * yv; }
        }
        v1 *= 2.0f;
        for (int o = 32; o > 0; o >>= 1) {
            v1 += __shfl_down(v1, o, 64);
            v2 += __shfl_down(v2, o, 64);
        }
        if (lane == 0) { r1s[wid] = v1; r2s[wid] = v2; }
        __syncthreads();
        if (tid == 0) {
            float ld = r1s[0] + r1s[1] + r1s[2] + r1s[3];
            float yy = r2s[0] + r2s[1] + r2s[2] + r2s[3] + scal[2];  // chunks 0..14 + 15
            float se = se_p[0], inv = 1.0f / se;
            float rr = scal[0], st = scal[1];
            float quad = rr * inv - inv * inv * (st - inv * yy);
            float logdetV = (float)NN * __logf(se) + ld;
            out[0] = 0.5f * (float)NN * 1.8378770664093453f + 0.5f * logdetV + 0.5f * quad;
        }
    }
}

extern "C" void kernel_launch(void* const* d_in, const int* in_sizes, int n_in,
                              void* d_out, int out_size, void* d_ws, size_t ws_size,
                              hipStream_t stream) {
    const float* yt   = (const float*)d_in[0];
    const float* yp   = (const float*)d_in[1];
    const int*   idx  = (const int*)d_in[2];
    const float* dist = (const float*)d_in[3];
    const float* se   = (const float*)d_in[4];
    const float* sbs  = (const float*)d_in[5];
    float* out = (float*)d_out;

    float* W    = (float*)d_ws;
    float* A    = W;                            // 1025 x LDA
    int*   c    = (int*)(W + AF);               // 1024 ints
    float* s    = W + AF + 1024;                // 1024
    float* scal = W + AF + 2048;                // rr, st, wyy (+pad)
    unsigned* barc = (unsigned*)(W + AF + 2080);  // 8 counters, stride 32 words
    unsigned* root = (unsigned*)(W + AF + 2368);  // own line
    unsigned* flag = (unsigned*)(W + AF + 2400);  // own line
    float* t    = W + AF + 2560;                // 1024
    float* w    = t + 1024;                     // 1024
    float* sqc  = w + 1024;                     // 1024

    // zero c, s, scal, barrier counters, root, flag in ONE contiguous memset
    (void)hipMemsetAsync(c, 0, 2432 * sizeof(float), stream);

    k_all<<<dim3(NB), dim3(256), 0, stream>>>(yt, yp, idx, dist, se, sbs,
                                              A, c, s, scal, t, w, sqc,
                                              barc, root, flag, out);
}

// Round 5
// 913.385 us; speedup vs baseline: 1.4008x; 1.0483x over previous
//
#include <hip/hip_runtime.h>
#include <math.h>

#define NN 4096
#define QQ 1024
#define LDA 1032              // padded leading dim (16B-aligned rows)
#define AF (1025 * 1032)      // floats occupied by bordered matrix A (1025 rows)
#define NB 136                // grid: max fused-syrk tiles at p=0 is 135

// sync area layout (32-bit words, offsets from sy base; 128B line separation)
#define SY_CNT1 0      // slow-barrier counter
#define SY_FLAG1 32    // slow-barrier flag
#define SY_POP 64      // pop[x] at SY_POP + x*32   (x < 8)
#define SY_CNTF 320    // fast arrival cnt[x] at SY_CNTF + x*32
#define SY_ROOT 576    // fast root counter
#define SY_MBOX 608    // mailbox[b] at SY_MBOX + b*32  (b < NB)
#define SY_WORDS 4960  // total words incl. mbox end (608+136*32=4960)

__device__ __forceinline__ unsigned read_xcc() {
    // HW_REG_XCC_ID = 20, offset 0, size 32  [measured: learn_hip m09 -> 0..7]
    return __builtin_amdgcn_s_getreg((31 << 11) | 20) & 7u;
}

// slow bootstrap barrier (used once, before pop[] is known)
__device__ __forceinline__ void gsync_slow(unsigned* sy) {
    __syncthreads();
    if (threadIdx.x == 0) {
        __scoped_atomic_thread_fence(__ATOMIC_RELEASE, __MEMORY_SCOPE_DEVICE);
        unsigned old = __hip_atomic_fetch_add(&sy[SY_CNT1], 1u,
                                              __ATOMIC_RELAXED, __HIP_MEMORY_SCOPE_AGENT);
        if (old + 1 == NB)
            __hip_atomic_store(&sy[SY_FLAG1], 1u, __ATOMIC_RELEASE, __HIP_MEMORY_SCOPE_AGENT);
        while (__hip_atomic_load(&sy[SY_FLAG1], __ATOMIC_RELAXED, __HIP_MEMORY_SCOPE_AGENT) < 1u)
            __builtin_amdgcn_s_sleep(1);
        __scoped_atomic_thread_fence(__ATOMIC_ACQUIRE, __MEMORY_SCOPE_DEVICE);
    }
    __syncthreads();
}

// fast barrier: per-XCD-last release fence (1 wbl2/XCD), mailbox broadcast wake
__device__ __forceinline__ void gsync_fast(unsigned* sy, unsigned fep,
                                           unsigned myx, unsigned mypop, unsigned nx) {
    __syncthreads();   // drains vmcnt -> this block's stores are in its XCD L2
    if (threadIdx.x == 0) {
        unsigned old = __hip_atomic_fetch_add(&sy[SY_CNTF + myx * 32], 1u,
                                              __ATOMIC_RELAXED, __HIP_MEMORY_SCOPE_AGENT);
        if (old + 1 == fep * mypop) {     // last arriver on this XCD this epoch
            // flush this XCD's L2 (covers ALL its blocks' stores)
            __scoped_atomic_thread_fence(__ATOMIC_RELEASE, __MEMORY_SCOPE_DEVICE);
            unsigned r = __hip_atomic_fetch_add(&sy[SY_ROOT], 1u,
                                                __ATOMIC_RELAXED, __HIP_MEMORY_SCOPE_AGENT);
            if (r + 1 == fep * nx) {      // all XCDs flushed -> wake everyone
                for (int b = 0; b < NB; ++b)
                    __hip_atomic_store(&sy[SY_MBOX + b * 32], fep,
                                       __ATOMIC_RELAXED, __HIP_MEMORY_SCOPE_AGENT);
            }
        }
        while (__hip_atomic_load(&sy[SY_MBOX + blockIdx.x * 32],
                                 __ATOMIC_RELAXED, __HIP_MEMORY_SCOPE_AGENT) < fep)
            __builtin_amdgcn_s_sleep(1);
        __scoped_atomic_thread_fence(__ATOMIC_ACQUIRE, __MEMORY_SCOPE_DEVICE);  // inv only
    }
    __syncthreads();
}

// ======== rank-2 register potrf of a 64x64 tile (256 threads) ========
__device__ __forceinline__ void potrf64_run(float (&x)[16], int i, int q,
                                            float2 (&col2)[2][64]) {
#pragma unroll
    for (int qk = 0; qk < 4; ++qk) {
#pragma unroll
        for (int c2 = 0; c2 < 8; ++c2) {
            const int k = qk * 16 + 2 * c2;
            const int ck = 2 * c2;
            const int b = c2 & 1;
            if (q == qk) {                        // wave-uniform
                float xk = x[ck];
                float d0 = __shfl(xk, k, 64);
                float rs0 = rsqrtf(d0);
                float l0 = (i == k) ? d0 * rs0 : xk * rs0;
                if (i >= k) x[ck] = l0;
                float lk1 = __shfl(l0, k + 1, 64);
                float x1v = fmaf(-l0, lk1, x[ck + 1]);
                float d1 = __shfl(x1v, k + 1, 64);
                float rs1 = rsqrtf(d1);
                float l1 = (i == k + 1) ? d1 * rs1 : x1v * rs1;
                if (i >= k + 1) x[ck + 1] = l1;
                col2[b][i] = make_float2(l0, l1);
            }
            __syncthreads();
            if (16 * q + 15 > k + 1 && i > k) {
                float2 lp = col2[b][i];
                const float4* cp = (const float4*)(&col2[b][16 * q]);
#pragma unroll
                for (int m2 = 0; m2 < 8; ++m2) {
                    float4 v = cp[m2];
                    if (16 * q + 2 * m2 > k + 1)
                        x[2 * m2] = fmaf(-lp.x, v.x, fmaf(-lp.y, v.y, x[2 * m2]));
                    if (16 * q + 2 * m2 + 1 > k + 1)
                        x[2 * m2 + 1] = fmaf(-lp.x, v.z, fmaf(-lp.y, v.w, x[2 * m2 + 1]));
                }
            }
        }
    }
}

// ======== template-unrolled trsm helpers ========
template<int K, int M>
struct TAcc {
    static __device__ __forceinline__ void run(const float (&Lb)[64][65], const float (&x)[64],
                                               float& a0, float& a1) {
        if constexpr (M < K)     a0 = fmaf(-Lb[K][M], x[M], a0);
        if constexpr (M + 1 < K) a1 = fmaf(-Lb[K][M + 1], x[M + 1], a1);
        if constexpr (M + 2 < K) TAcc<K, M + 2>::run(Lb, x, a0, a1);
    }
};
template<int K>
struct TStep {
    static __device__ __forceinline__ void run(const float (&Lb)[64][65], const float (&dinv)[64],
                                               float (&x)[64]) {
        if constexpr (K < 64) {
            float a0 = x[K], a1 = 0.f;
            TAcc<K, 0>::run(Lb, x, a0, a1);
            x[K] = (a0 + a1) * dinv[K];
            TStep<K + 1>::run(Lb, dinv, x);
        }
    }
};

// ======== single persistent kernel: 1 slow + 17 fast barriers ========
__global__ __launch_bounds__(256, 1) void k_all(
    const float* __restrict__ yt, const float* __restrict__ yp,
    const int* __restrict__ idx, const float* __restrict__ dist,
    const float* __restrict__ se_p, const float* __restrict__ sbs,
    float* __restrict__ A, int* __restrict__ c, float* __restrict__ s,
    float* __restrict__ scal, float* __restrict__ t, float* __restrict__ w,
    float* __restrict__ sqc, unsigned* __restrict__ sy, float* __restrict__ out) {
    const int bid = blockIdx.x, tid = threadIdx.x;
    const int lane = tid & 63, wid = tid >> 6;
    unsigned fep = 0;
    unsigned myx = 0, mypop = 0, nx = 0;

    __shared__ __align__(16) float PrRaw[64 * 68];
    __shared__ __align__(16) float PcRaw[64 * 68];
    __shared__ float2 col2[2][64];
    __shared__ float Lb[64][65];
    __shared__ float dinv[64];
    __shared__ float red[4];
    __shared__ float r1s[4], r2s[4];
    __shared__ float wl[64];

    // ---- startup: register this block's XCD residency ----
    if (tid == 0) {
        myx = read_xcc();
        __hip_atomic_fetch_add(&sy[SY_POP + myx * 32], 1u,
                               __ATOMIC_RELAXED, __HIP_MEMORY_SCOPE_AGENT);
    }

    // ---- phase 1: stats ----
    if (bid < NN / 256) {
        int i = bid * 256 + tid;
        float r = yt[i] - yp[i];
        int q = idx[i];
        atomicAdd(&s[q], r);
        atomicAdd(&c[q], 1);
        float v = r * r;
        for (int o = 32; o > 0; o >>= 1) v += __shfl_down(v, o, 64);
        if (lane == 0) red[wid] = v;
        __syncthreads();
        if (tid == 0) atomicAdd(&scal[0], red[0] + red[1] + red[2] + red[3]);
    }
    gsync_slow(sy);   // also publishes pop[]

    if (tid == 0) {   // thread0-private barrier parameters
        mypop = __hip_atomic_load(&sy[SY_POP + myx * 32],
                                  __ATOMIC_RELAXED, __HIP_MEMORY_SCOPE_AGENT);
        for (int x = 0; x < 8; ++x)
            nx += (__hip_atomic_load(&sy[SY_POP + x * 32],
                                     __ATOMIC_RELAXED, __HIP_MEMORY_SCOPE_AGENT) != 0u);
    }

    // ---- phase 2: matvec: t = D s ; w = sqrt(c)*t ; sqc ; st = s.t ----
    {
        float sb0 = sbs[0];
        float inv2 = 1.0f / (2.0f * sbs[1]);
        for (int i = bid; i < QQ; i += NB) {
            const float* dr = dist + (size_t)i * QQ;
            float acc = 0.f;
            for (int j = tid; j < QQ; j += 256)
                acc += __expf(-dr[j] * inv2) * s[j];
            for (int o = 32; o > 0; o >>= 1) acc += __shfl_down(acc, o, 64);
            if (lane == 0) red[wid] = acc;
            __syncthreads();
            if (tid == 0) {
                float tot = (red[0] + red[1] + red[2] + red[3]) * sb0;
                t[i] = tot;
                float sq = sqrtf((float)c[i]);
                sqc[i] = sq;
                w[i] = sq * tot;
                atomicAdd(&scal[1], s[i] * tot);
            }
            __syncthreads();
        }
    }
    gsync_fast(sy, ++fep, myx, mypop, nx);

    // ---- phase 3: build bordered S (rows >= 64 + w-row) + fused potrf0 (block 0) ----
    // Rows 0..63 beyond col 63 are never read again, so block 0 builds only the
    // 64x64 diagonal tile (in LDS), factors it, and writes the factored tile.
    {
        float sb0 = sbs[0];
        float inv2 = 1.0f / (2.0f * sbs[1]);
        float inv_se = 1.0f / se_p[0];
        if (bid == 0) {
            for (int kk = tid; kk < 4096; kk += 256) {
                int i = kk >> 6, j = kk & 63;
                float qi = sqc[i] * inv_se * sb0;
                PcRaw[i * 65 + j] = ((i == j) ? 1.0f : 0.0f)
                                  + qi * sqc[j] * __expf(-dist[(size_t)i * QQ + j] * inv2);
            }
            __syncthreads();
            int i = lane, q = wid;
            float x[16];
#pragma unroll
            for (int m = 0; m < 16; ++m) x[m] = PcRaw[i * 65 + 16 * q + m];
            potrf64_run(x, i, q, col2);
            float* row = A + (size_t)i * LDA + 16 * q;
#pragma unroll
            for (int m4 = 0; m4 < 4; ++m4)
                ((float4*)row)[m4] = make_float4(x[4 * m4], x[4 * m4 + 1],
                                                 x[4 * m4 + 2], x[4 * m4 + 3]);
        } else {
            for (int i = 64 + (bid - 1); i <= QQ; i += (NB - 1)) {
                if (i == QQ) {
                    for (int j = tid; j < QQ; j += 256) A[(size_t)QQ * LDA + j] = w[j];
                } else {
                    float qi = sqc[i] * inv_se * sb0;
                    const float* dr = dist + (size_t)i * QQ;
                    float* ar_ = A + (size_t)i * LDA;
                    for (int j = tid; j < QQ; j += 256)
                        ar_[j] = ((i == j) ? 1.0f : 0.0f) + qi * sqc[j] * __expf(-dr[j] * inv2);
                }
            }
        }
    }
    gsync_fast(sy, ++fep, myx, mypop, nx);

    // ---- panel loop: ONE phase per panel (fused trsm-in-LDS + syrk + diag potrf) ----
#pragma unroll 1
    for (int p = 0; p < 15; ++p) {
        int t0v = (p + 1) * 64;
        int rows = (QQ + 1) - t0v;
        int nr = (rows + 63) >> 6;          // last row-tile is exactly row QQ
        int ncol = (QQ - t0v) / 64;
        // triangular tile enumeration: cnt(by) = min(by+1, ncol)
        int by = -1, bx = 0, rem = bid;
        for (int b = 0; b < nr; ++b) {
            int cn = (b + 1 < ncol) ? (b + 1) : ncol;
            if (rem < cn) { by = b; bx = rem; break; }
            rem -= cn;
        }
        if (by >= 0) {
            int r0 = t0v + by * 64;
            int c0 = t0v + bx * 64;
            bool wrow = (by == nr - 1);           // tile row = row QQ only
            bool same_rc = (bx == by) && !wrow;   // diag tile (incl. dfuse)
            bool dfuse = (bx == 0 && by == 0);
            int pc0 = p * 64;
            const float* db = A + (size_t)pc0 * (LDA + 1);
            // stage raw panel tiles + Lb + dinv
            for (int idx2 = tid; idx2 < 1024; idx2 += 256) {
                int rr = idx2 >> 4, c4 = idx2 & 15;
                int gr = r0 + rr;
                float4 v = make_float4(0.f, 0.f, 0.f, 0.f);
                if (gr <= QQ) v = *(const float4*)(A + (size_t)gr * LDA + pc0 + 4 * c4);
                *(float4*)(PrRaw + rr * 68 + 4 * c4) = v;
                if (!same_rc) {
                    float4 u = *(const float4*)(A + (size_t)(c0 + rr) * LDA + pc0 + 4 * c4);
                    *(float4*)(PcRaw + rr * 68 + 4 * c4) = u;
                }
            }
            for (int kk = tid; kk < 4096; kk += 256) {
                int ii = kk >> 6, jj = kk & 63;
                Lb[ii][jj] = db[(size_t)ii * LDA + jj];
            }
            if (tid < 64) dinv[tid] = 1.0f / db[(size_t)tid * (LDA + 1)];
            __syncthreads();
            // trsm in LDS: wave 0 -> PrRaw rows, wave 1 -> PcRaw rows
            if (wid == 0 && wrow) {
                float xv = PrRaw[lane];
                for (int k = 0; k < 64; ++k) {
                    if (lane == k) xv *= dinv[k];
                    float xk = __shfl(xv, k, 64);
                    if (lane > k) xv = fmaf(-Lb[lane][k], xk, xv);
                }
                PrRaw[lane] = xv;
                if (bx == 0) {
                    float v = xv * xv;
                    for (int o = 32; o > 0; o >>= 1) v += __shfl_down(v, o, 64);
                    if (lane == 0) atomicAdd(&scal[2], v);
                }
            } else {
                float* tp = nullptr;
                if (wid == 0) tp = PrRaw + lane * 68;               // !wrow here
                else if (wid == 1 && !same_rc) tp = PcRaw + lane * 68;
                if (tp) {
                    float x[64];
#pragma unroll
                    for (int m = 0; m < 64; ++m) x[m] = tp[m];
                    TStep<0>::run(Lb, dinv, x);
#pragma unroll
                    for (int m = 0; m < 64; ++m) tp[m] = x[m];
                }
            }
            __syncthreads();
            // syrk from trsm'd LDS tiles
            const float* PB = same_rc ? PrRaw : PcRaw;
            int tx = tid & 15, ty = tid >> 4;
            float acc[4][4];
#pragma unroll
            for (int ii = 0; ii < 4; ++ii)
#pragma unroll
                for (int jj = 0; jj < 4; ++jj) acc[ii][jj] = 0.f;
            float4 ar4[4], br4[4];
#pragma unroll 4
            for (int k4 = 0; k4 < 16; ++k4) {
#pragma unroll
                for (int ii = 0; ii < 4; ++ii)
                    ar4[ii] = *(const float4*)(PrRaw + (ty + 16 * ii) * 68 + 4 * k4);
#pragma unroll
                for (int jj = 0; jj < 4; ++jj)
                    br4[jj] = *(const float4*)(PB + (tx + 16 * jj) * 68 + 4 * k4);
#pragma unroll
                for (int ii = 0; ii < 4; ++ii)
#pragma unroll
                    for (int jj = 0; jj < 4; ++jj) {
                        acc[ii][jj] = fmaf(ar4[ii].x, br4[jj].x, acc[ii][jj]);
                        acc[ii][jj] = fmaf(ar4[ii].y, br4[jj].y, acc[ii][jj]);
                        acc[ii][jj] = fmaf(ar4[ii].z, br4[jj].z, acc[ii][jj]);
                        acc[ii][jj] = fmaf(ar4[ii].w, br4[jj].w, acc[ii][jj]);
                    }
            }
            if (!dfuse) {
#pragma unroll
                for (int ii = 0; ii < 4; ++ii) {
                    int rr = r0 + ty + 16 * ii;
                    if (rr <= QQ) {
#pragma unroll
                        for (int jj = 0; jj < 4; ++jj) {
                            float* pa = A + (size_t)rr * LDA + c0 + tx + 16 * jj;
                            *pa -= acc[ii][jj];
                        }
                    }
                }
            } else {
                // updated next diag tile -> LDS (stride-65 view of PcRaw), then factor
#pragma unroll
                for (int ii = 0; ii < 4; ++ii) {
                    int lr = ty + 16 * ii;
#pragma unroll
                    for (int jj = 0; jj < 4; ++jj) {
                        int lc = tx + 16 * jj;
                        float old = A[(size_t)(r0 + lr) * LDA + c0 + lc];
                        PcRaw[lr * 65 + lc] = old - acc[ii][jj];
                    }
                }
                __syncthreads();
                int i = tid & 63, q = tid >> 6;
                float x[16];
#pragma unroll
                for (int m = 0; m < 16; ++m) x[m] = PcRaw[i * 65 + 16 * q + m];
                potrf64_run(x, i, q, col2);
                float* row = A + (size_t)(r0 + i) * LDA + c0 + 16 * q;
#pragma unroll
                for (int m4 = 0; m4 < 4; ++m4)
                    ((float4*)row)[m4] = make_float4(x[4 * m4], x[4 * m4 + 1],
                                                     x[4 * m4 + 2], x[4 * m4 + 3]);
            }
        }
        gsync_fast(sy, ++fep, myx, mypop, nx);
    }

    // ---- final: block 0 solves bordered chunk 15 in LDS and reduces ----
    if (bid == 0) {
        const float* db = A + (size_t)960 * LDA + 960;  // last diag tile (factored)
        for (int kk = tid; kk < 4096; kk += 256) {
            int ii = kk >> 6, jj = kk & 63;
            Lb[ii][jj] = db[(size_t)ii * LDA + jj];
        }
        __syncthreads();
        if (tid < 64) {
            float xv = A[(size_t)QQ * LDA + 960 + tid];
            for (int k = 0; k < 64; ++k) {
                if (tid == k) xv /= Lb[k][k];
                float xk = __shfl(xv, k, 64);
                if (tid > k) xv = fmaf(-Lb[tid][k], xk, xv);
            }
            wl[tid] = xv;
        }
        __syncthreads();
        float v1 = 0.f, v2 = 0.f;
        for (int i = tid; i < QQ; i += 256) {
            v1 += __logf(A[(size_t)i * LDA + i]);
            if (i >= 960) { float yv = wl[i - 960]; v2 += yv * yv; }
        }
        v1 *= 2.0f;
        for (int o = 32; o > 0; o >>= 1) {
            v1 += __shfl_down(v1, o, 64);
            v2 += __shfl_down(v2, o, 64);
        }
        if (lane == 0) { r1s[wid] = v1; r2s[wid] = v2; }
        __syncthreads();
        if (tid == 0) {
            float ld = r1s[0] + r1s[1] + r1s[2] + r1s[3];
            float yy = r2s[0] + r2s[1] + r2s[2] + r2s[3] + scal[2];  // chunks 0..14 + 15
            float se = se_p[0], inv = 1.0f / se;
            float rr = scal[0], st = scal[1];
            float quad = rr * inv - inv * inv * (st - inv * yy);
            float logdetV = (float)NN * __logf(se) + ld;
            out[0] = 0.5f * (float)NN * 1.8378770664093453f + 0.5f * logdetV + 0.5f * quad;
        }
    }
}

extern "C" void kernel_launch(void* const* d_in, const int* in_sizes, int n_in,
                              void* d_out, int out_size, void* d_ws, size_t ws_size,
                              hipStream_t stream) {
    const float* yt   = (const float*)d_in[0];
    const float* yp   = (const float*)d_in[1];
    const int*   idx  = (const int*)d_in[2];
    const float* dist = (const float*)d_in[3];
    const float* se   = (const float*)d_in[4];
    const float* sbs  = (const float*)d_in[5];
    float* out = (float*)d_out;

    float* W    = (float*)d_ws;
    float* A    = W;                              // 1025 x LDA
    int*   c    = (int*)(W + AF);                 // 1024 ints
    float* s    = W + AF + 1024;                  // 1024
    float* scal = W + AF + 2048;                  // rr, st, wyy (+pad)
    unsigned* sy = (unsigned*)(W + AF + 2080);    // sync area (SY_WORDS words)
    float* t    = W + AF + 2080 + SY_WORDS;       // 1024
    float* w    = t + 1024;                       // 1024
    float* sqc  = w + 1024;                       // 1024

    // zero c, s, scal, and the whole sync area in ONE contiguous memset
    (void)hipMemsetAsync(c, 0, (2080 + SY_WORDS) * sizeof(float), stream);

    k_all<<<dim3(NB), dim3(256), 0, stream>>>(yt, yp, idx, dist, se, sbs,
                                              A, c, s, scal, t, w, sqc, sy, out);
}